// Round 11
// baseline (314.011 us; speedup 1.0000x reference)
//
#include <hip/hip_runtime.h>
#include <math.h>

#define NPTS    131072
#define FEAT    64
#define KCLUS   2048
#define KQ      512      // clusters per blockIdx.y quarter
#define CH1     128      // clusters staged per LDS chunk
#define PPW     64       // points per wave (4 MFMA row-tiles)
#define WPB     4        // waves per 256-thread block (wave = 64 on CDNA!)
#define PPB     (PPW * WPB)   // 256 points per block
#define CANDC   8        // per-lane register candidate slots (per quarter)

typedef __attribute__((ext_vector_type(8))) short frag_ab;   // 8 bf16
typedef __attribute__((ext_vector_type(4))) float frag_cd;   // 4 fp32 acc

__device__ __forceinline__ short f2bf(float f) {
    unsigned u = __float_as_uint(f);
    u += 0x7FFFu + ((u >> 16) & 1u);
    return (short)(u >> 16);
}
// monotone float<->u32 (r3/r10-proven)
__device__ __forceinline__ unsigned fmono(float e) {
    unsigned u = __float_as_uint(e);
    return u ^ (unsigned)(((int)u >> 31) | 0x80000000);
}
__device__ __forceinline__ float fmono_dec(unsigned m) {
    unsigned u = (m & 0x80000000u) ? (m ^ 0x80000000u) : ~m;
    return __uint_as_float(u);
}

// Exact fp32 distance term (cn - 2 x.c): IDENTICAL single-chain FMA order to
// rounds 1-3/7/10 (matches numpy argmin on this data, absmax 0 x6).
__device__ __forceinline__ float exact_dist(const float* __restrict__ x,
                                            const float* __restrict__ c,
                                            float cnv, int p, int kk) {
    const float4* xr4 = (const float4*)&x[(size_t)p * FEAT];
    const float4* cr4 = (const float4*)&c[(size_t)kk * FEAT];
    float s = 0.f;
#pragma unroll
    for (int j = 0; j < 16; ++j) {
        float4 a4 = xr4[j], b4 = cr4[j];
        s = fmaf(a4.x, b4.x, s); s = fmaf(a4.y, b4.y, s);
        s = fmaf(a4.z, b4.z, s); s = fmaf(a4.w, b4.w, s);
    }
    return fmaf(-2.f, s, cnv);
}

// ---------------------------------------------------------------------------
// cprep: exact fp32 cnorm, cbs_t = bf16(-2c) part-major [part=f/8][k][8]
// (proven conflict-free + correct B layout), cmax = max||c||.
// ---------------------------------------------------------------------------
__global__ void cprep_kernel(const float* __restrict__ c, float* __restrict__ cnorm,
                             short* __restrict__ cbs_t, float* __restrict__ cmax) {
    int k = blockIdx.x * blockDim.x + threadIdx.x;
    if (k >= KCLUS) return;
    const float4* row = (const float4*)&c[k * FEAT];
    float s = 0.f;
#pragma unroll
    for (int j = 0; j < 16; ++j) {
        float4 v = row[j];
        s = fmaf(v.x, v.x, s); s = fmaf(v.y, v.y, s);
        s = fmaf(v.z, v.z, s); s = fmaf(v.w, v.w, s);
        short4 b;
        b.x = f2bf(-2.f * v.x); b.y = f2bf(-2.f * v.y);
        b.z = f2bf(-2.f * v.z); b.w = f2bf(-2.f * v.w);
        *(short4*)&cbs_t[((size_t)(j >> 1) * KCLUS + k) * 8 + (j & 1) * 4] = b;
    }
    cnorm[k] = s;
    atomicMax((int*)cmax, __float_as_int(sqrtf(s)));  // positive: int-max == float-max
}

// Stage one 128-cluster chunk (16 KB) into part-major LDS. 4 x 16B per thread.
__device__ __forceinline__ void stage_chunk(const short* __restrict__ cbs_t,
                                            const float* __restrict__ cnorm,
                                            int k0, int tid,
                                            short* csh, float* cnsh) {
#pragma unroll
    for (int j = 0; j < 4; ++j) {
        int f = j * 256 + tid;              // f = p8*128 + i
        int p8 = f >> 7, i = f & 127;
        *(frag_ab*)&csh[f * 8] =
            *(const frag_ab*)&cbs_t[((size_t)p8 * KCLUS + k0 + i) * 8];
    }
    if (tid < CH1) cnsh[tid] = cnorm[k0 + tid];
}

// ---------------------------------------------------------------------------
// PASS 1: approx min over this block's cluster QUARTER; publish per-point
// global min via u32 monotone atomicMin (r3/r10-proven). PPW=64: 4 row-tiles
// per wave -> 8 MFMAs per ds_read pair, 4 independent MFMA chains.
// ---------------------------------------------------------------------------
__global__ __launch_bounds__(256) void pass1_kernel(
    const float* __restrict__ x, const short* __restrict__ cbs_t,
    const float* __restrict__ cnorm, unsigned* __restrict__ pmin)
{
    __shared__ short csh[8 * CH1 * 8];   // 16 KB
    __shared__ float cnsh[CH1];

    const int tid = threadIdx.x, wv = tid >> 6, lane = tid & 63;
    const int col = lane & 15, q = lane >> 4;
    const int pt0 = blockIdx.x * PPB + wv * PPW;
    const int kbase = blockIdx.y * KQ;

    frag_ab A[4][2];
#pragma unroll
    for (int rt = 0; rt < 4; ++rt)
#pragma unroll
        for (int kh = 0; kh < 2; ++kh) {
            const float4* xp = (const float4*)&x[(size_t)(pt0 + rt * 16 + col) * FEAT + kh * 32 + q * 8];
            float4 v0 = xp[0], v1 = xp[1];
            frag_ab a;
            a[0] = f2bf(v0.x); a[1] = f2bf(v0.y); a[2] = f2bf(v0.z); a[3] = f2bf(v0.w);
            a[4] = f2bf(v1.x); a[5] = f2bf(v1.y); a[6] = f2bf(v1.z); a[7] = f2bf(v1.w);
            A[rt][kh] = a;
        }

    float m[4][4];
#pragma unroll
    for (int rt = 0; rt < 4; ++rt)
#pragma unroll
        for (int r = 0; r < 4; ++r) m[rt][r] = INFINITY;

    for (int c8 = 0; c8 < KQ / CH1; ++c8) {
        __syncthreads();
        stage_chunk(cbs_t, cnorm, kbase + c8 * CH1, tid, csh, cnsh);
        __syncthreads();

#pragma unroll 2
        for (int ct = 0; ct < CH1 / 16; ++ct) {
            const int lc = ct * 16 + col;
            frag_ab b0 = *(const frag_ab*)&csh[(q * CH1 + lc) * 8];
            frag_ab b1 = *(const frag_ab*)&csh[((4 + q) * CH1 + lc) * 8];
            const float cnv = cnsh[lc];
#pragma unroll
            for (int rt = 0; rt < 4; ++rt) {
                frag_cd acc = {cnv, cnv, cnv, cnv};
                acc = __builtin_amdgcn_mfma_f32_16x16x32_bf16(A[rt][0], b0, acc, 0, 0, 0);
                acc = __builtin_amdgcn_mfma_f32_16x16x32_bf16(A[rt][1], b1, acc, 0, 0, 0);
                m[rt][0] = fminf(m[rt][0], acc[0]);
                m[rt][1] = fminf(m[rt][1], acc[1]);
                m[rt][2] = fminf(m[rt][2], acc[2]);
                m[rt][3] = fminf(m[rt][3], acc[3]);
            }
        }
    }

#pragma unroll
    for (int rt = 0; rt < 4; ++rt)
#pragma unroll
        for (int r = 0; r < 4; ++r) {
            float mm = m[rt][r];
            mm = fminf(mm, __shfl_xor(mm, 1));
            mm = fminf(mm, __shfl_xor(mm, 2));
            mm = fminf(mm, __shfl_xor(mm, 4));
            mm = fminf(mm, __shfl_xor(mm, 8));
            if (col == 0)
                atomicMin(&pmin[pt0 + rt * 16 + q * 4 + r], fmono(mm));
        }
}

// ---------------------------------------------------------------------------
// PASS 2: threshold from global pmin; per-lane register candidate capture
// (r7/r10-proven); exact refine; combine quarters via global u64 atomicMin
// on (fmono(d)<<32)|k keys (r3/r10-proven).
// ---------------------------------------------------------------------------
__global__ __launch_bounds__(256) void pass2_kernel(
    const float* __restrict__ x, const float* __restrict__ c,
    const short* __restrict__ cbs_t, const float* __restrict__ cnorm,
    const float* __restrict__ cmaxp, const unsigned* __restrict__ pmin,
    unsigned long long* __restrict__ best)
{
    __shared__ short csh[8 * CH1 * 8];
    __shared__ float cnsh[CH1];

    const int tid = threadIdx.x, wv = tid >> 6, lane = tid & 63;
    const int col = lane & 15, q = lane >> 4;
    const int pt0 = blockIdx.x * PPB + wv * PPW;
    const int kbase = blockIdx.y * KQ;

    // A-frags + inline row norms (r10-proven): butterfly over lane bits 16/32.
    frag_ab A[4][2];
    float nrm[4];
#pragma unroll
    for (int rt = 0; rt < 4; ++rt) {
        float ps = 0.f;
#pragma unroll
        for (int kh = 0; kh < 2; ++kh) {
            const float4* xp = (const float4*)&x[(size_t)(pt0 + rt * 16 + col) * FEAT + kh * 32 + q * 8];
            float4 v0 = xp[0], v1 = xp[1];
            frag_ab a;
            a[0] = f2bf(v0.x); a[1] = f2bf(v0.y); a[2] = f2bf(v0.z); a[3] = f2bf(v0.w);
            a[4] = f2bf(v1.x); a[5] = f2bf(v1.y); a[6] = f2bf(v1.z); a[7] = f2bf(v1.w);
            A[rt][kh] = a;
            ps = fmaf(v0.x, v0.x, ps); ps = fmaf(v0.y, v0.y, ps);
            ps = fmaf(v0.z, v0.z, ps); ps = fmaf(v0.w, v0.w, ps);
            ps = fmaf(v1.x, v1.x, ps); ps = fmaf(v1.y, v1.y, ps);
            ps = fmaf(v1.z, v1.z, ps); ps = fmaf(v1.w, v1.w, ps);
        }
        ps += __shfl_xor(ps, 16);
        ps += __shfl_xor(ps, 32);
        nrm[rt] = sqrtf(ps);
    }

    // Threshold: global min (pmin) + 0.034*||x||*cmax >= min + 2*eps_bf16.
    const float cmax = *cmaxp;
    float t[4][4];
#pragma unroll
    for (int rt = 0; rt < 4; ++rt)
#pragma unroll
        for (int r = 0; r < 4; ++r) {
            const int p = pt0 + rt * 16 + q * 4 + r;
            float xnp = __shfl(nrm[rt], q * 4 + r);
            t[rt][r] = fmono_dec(pmin[p]) + 0.034f * xnp * cmax;
        }

    unsigned codes[CANDC];
    int ccnt = 0;

    for (int c8 = 0; c8 < KQ / CH1; ++c8) {
        __syncthreads();
        stage_chunk(cbs_t, cnorm, kbase + c8 * CH1, tid, csh, cnsh);
        __syncthreads();

        const int k0 = kbase + c8 * CH1;
#pragma unroll 2
        for (int ct = 0; ct < CH1 / 16; ++ct) {
            const int lc = ct * 16 + col;
            frag_ab b0 = *(const frag_ab*)&csh[(q * CH1 + lc) * 8];
            frag_ab b1 = *(const frag_ab*)&csh[((4 + q) * CH1 + lc) * 8];
            const float cnv = cnsh[lc];
            const int kk = k0 + lc;
#pragma unroll
            for (int rt = 0; rt < 4; ++rt) {
                frag_cd acc = {cnv, cnv, cnv, cnv};
                acc = __builtin_amdgcn_mfma_f32_16x16x32_bf16(A[rt][0], b0, acc, 0, 0, 0);
                acc = __builtin_amdgcn_mfma_f32_16x16x32_bf16(A[rt][1], b1, acc, 0, 0, 0);
#pragma unroll
                for (int r = 0; r < 4; ++r) {
                    if (acc[r] <= t[rt][r]) {   // rare
                        unsigned code = ((unsigned)(rt * 16 + q * 4 + r) << 11) | (unsigned)kk;
#pragma unroll
                        for (int s = 0; s < CANDC; ++s)
                            if (s == ccnt) codes[s] = code;
                        ccnt++;
                    }
                }
            }
        }
    }

    const bool anyovf = __any(ccnt > CANDC);

    if (!anyovf) {
        float bestd[4][4];
        int   bestk[4][4];
#pragma unroll
        for (int rt = 0; rt < 4; ++rt)
#pragma unroll
            for (int r = 0; r < 4; ++r) { bestd[rt][r] = INFINITY; bestk[rt][r] = 0x7fffffff; }

        for (int i = 0; i < CANDC; ++i) {
            if (i < ccnt) {
                unsigned code = codes[i];
                int pl = (int)(code >> 11), kk = (int)(code & 2047u);
                float e = exact_dist(x, c, cnorm[kk], pt0 + pl, kk);
                int crt = pl >> 4, cr = pl & 3;
#pragma unroll
                for (int rt = 0; rt < 4; ++rt)
#pragma unroll
                    for (int r = 0; r < 4; ++r)
                        if (crt == rt && cr == r &&
                            (e < bestd[rt][r] || (e == bestd[rt][r] && kk < bestk[rt][r]))) {
                            bestd[rt][r] = e; bestk[rt][r] = kk;
                        }
            }
        }

#pragma unroll
        for (int rt = 0; rt < 4; ++rt) {
#pragma unroll
            for (int r = 0; r < 4; ++r) {
                float bd = bestd[rt][r]; int bk = bestk[rt][r];
#pragma unroll
                for (int mask = 1; mask <= 8; mask <<= 1) {
                    float od = __shfl_xor(bd, mask);
                    int   ok = __shfl_xor(bk, mask);
                    if (od < bd || (od == bd && ok < bk)) { bd = od; bk = ok; }
                }
                if (col == 0 && bk != 0x7fffffff) {
                    unsigned long long key =
                        ((unsigned long long)fmono(bd) << 32) | (unsigned)bk;
                    atomicMin(&best[pt0 + rt * 16 + q * 4 + r], key);
                }
            }
        }
    } else {
        // Overflow: whole-wave exact scan over THIS quarter's clusters.
        for (int pp = 0; pp < PPW; ++pp) {
            const int p = pt0 + pp;
            float bd = INFINITY; int bk = 0x7fffffff;
            for (int kk = kbase + lane; kk < kbase + KQ; kk += 64) {
                float e = exact_dist(x, c, cnorm[kk], p, kk);
                if (e < bd || (e == bd && kk < bk)) { bd = e; bk = kk; }
            }
#pragma unroll
            for (int mask = 1; mask <= 32; mask <<= 1) {
                float od = __shfl_xor(bd, mask);
                int   ok = __shfl_xor(bk, mask);
                if (od < bd || (od == bd && ok < bk)) { bd = od; bk = ok; }
            }
            if (lane == 0) {
                unsigned long long key =
                    ((unsigned long long)fmono(bd) << 32) | (unsigned)bk;
                atomicMin(&best[p], key);
            }
        }
    }
}

// decode: best key -> float assignment + compact u16 for the scatter scan.
__global__ void decode_kernel(const unsigned long long* __restrict__ best,
                              float* __restrict__ out_assign,
                              unsigned short* __restrict__ a16) {
    int i = blockIdx.x * blockDim.x + threadIdx.x;
    unsigned k = (unsigned)(best[i] & 2047ull);
    out_assign[i] = (float)k;
    a16[i] = (unsigned short)k;
}

// ---------------------------------------------------------------------------
// Scatter (r10-proven): block (cg, slice) owns clusters [8cg,8cg+8) over point
// slice [slice*16384, +16384). Ballot-collect, per-wave LDS accumulate,
// 8 atomic rows per block.
// ---------------------------------------------------------------------------
__global__ void scatter_kernel(const float* __restrict__ x,
                               const unsigned short* __restrict__ a16,
                               float* __restrict__ sums, int* __restrict__ counts) {
    __shared__ float wsum[4][8][64];   // 8 KB, per-wave private
    __shared__ int   wcnt[4][8];

    const int tid = threadIdx.x, wv = tid >> 6, lane = tid & 63;
    const int c0 = blockIdx.x * 8;

    for (int idx = tid; idx < 4 * 8 * 64; idx += 256) ((float*)wsum)[idx] = 0.f;
    if (tid < 32) ((int*)wcnt)[tid] = 0;
    __syncthreads();

    const int base = blockIdx.y * 16384 + wv * 4096;
#pragma unroll 1
    for (int it = 0; it < 64; ++it) {
        const int pbase = base + it * 64;
        int a = (int)a16[pbase + lane];                    // coalesced 128B
        unsigned long long mask = __ballot(a >= c0 && a < c0 + 8);
        while (mask) {
            int j = __ffsll((long long)mask) - 1;
            mask &= mask - 1;
            int cl = __shfl(a, j) - c0;
            float xv = x[(size_t)(pbase + j) * FEAT + lane];  // coalesced 256B row
            wsum[wv][cl][lane] += xv;                         // own slice: no race
            if (lane == 0) wcnt[wv][cl] += 1;
        }
    }
    __syncthreads();

    for (int idx = tid; idx < 512; idx += 256) {
        int cl = idx >> 6, ln = idx & 63;
        float s = wsum[0][cl][ln] + wsum[1][cl][ln] + wsum[2][cl][ln] + wsum[3][cl][ln];
        atomicAdd(&sums[(size_t)(c0 + cl) * FEAT + ln], s);
    }
    if (tid < 8) {
        int cc = wcnt[0][tid] + wcnt[1][tid] + wcnt[2][tid] + wcnt[3][tid];
        if (cc) atomicAdd(&counts[c0 + tid], cc);
    }
}

__global__ void update_kernel(const float* __restrict__ c,
                              const float* __restrict__ sums,
                              const int* __restrict__ counts,
                              float* __restrict__ out_upd) {
    int i = blockIdx.x * blockDim.x + threadIdx.x;
    if (i < KCLUS * FEAT) {
        int   k   = i >> 6;
        float cv  = c[i];
        int   cnt = counts[k];
        float nc  = (cnt > 0) ? (sums[i] / (float)cnt) : cv;
        out_upd[i] = 0.99f * cv + 0.01f * nc;
    }
}

extern "C" void kernel_launch(void* const* d_in, const int* in_sizes, int n_in,
                              void* d_out, int out_size, void* d_ws, size_t ws_size,
                              hipStream_t stream) {
    const float* x = (const float*)d_in[0];
    const float* c = (const float*)d_in[1];

    float* out        = (float*)d_out;
    float* out_assign = out;          // [0, N): assignments as float
    float* out_upd    = out + NPTS;   // [N, N + K*FEAT)

    // Workspace 2.52 MB (r10-proven layout).
    char* ws = (char*)d_ws;
    constexpr size_t O_CNORM = 0;                       // 8 KB
    constexpr size_t O_CBS   = 8192;                    // 256 KB
    constexpr size_t O_ZERO  = 8192 + 262144;           // 270336
    constexpr size_t O_CMAX  = O_ZERO;                  // 64 B
    constexpr size_t O_SUMS  = O_ZERO + 64;             // 512 KB
    constexpr size_t O_CNTS  = O_SUMS + 524288;         // 8 KB
    constexpr size_t ZERO_LEN = 64 + 524288 + 8192;     // 532544
    constexpr size_t O_FF    = O_ZERO + ZERO_LEN;       // 802880
    constexpr size_t O_PMIN  = O_FF;                    // 512 KB
    constexpr size_t O_BEST  = O_PMIN + 524288;         // 1 MB (8-aligned)
    constexpr size_t FF_LEN  = 524288 + 1048576;        // 1572864
    constexpr size_t O_A16   = O_FF + FF_LEN;           // 2375744, 256 KB

    float*    cnorm  = (float*)(ws + O_CNORM);
    short*    cbs_t  = (short*)(ws + O_CBS);
    float*    cmax   = (float*)(ws + O_CMAX);
    float*    sums   = (float*)(ws + O_SUMS);
    int*      counts = (int*)(ws + O_CNTS);
    unsigned* pmin   = (unsigned*)(ws + O_PMIN);
    unsigned long long* best = (unsigned long long*)(ws + O_BEST);
    unsigned short*     a16  = (unsigned short*)(ws + O_A16);

    hipMemsetAsync(ws + O_ZERO, 0, ZERO_LEN, stream);
    hipMemsetAsync(ws + O_FF, 0xFF, FF_LEN, stream);

    cprep_kernel<<<KCLUS / 256, 256, 0, stream>>>(c, cnorm, cbs_t, cmax);
    // PPW=64: 4 row-tiles/wave, 256 pts/block; k-split x4 keeps 2048 blocks.
    pass1_kernel<<<dim3(NPTS / PPB, KCLUS / KQ), 256, 0, stream>>>(x, cbs_t, cnorm, pmin);
    pass2_kernel<<<dim3(NPTS / PPB, KCLUS / KQ), 256, 0, stream>>>(x, c, cbs_t, cnorm,
                                                                   cmax, pmin, best);
    decode_kernel<<<NPTS / 256, 256, 0, stream>>>(best, out_assign, a16);
    scatter_kernel<<<dim3(KCLUS / 8, 8), 256, 0, stream>>>(x, a16, sums, counts);
    update_kernel<<<(KCLUS * FEAT) / 256, 256, 0, stream>>>(c, sums, counts, out_upd);
}

// Round 12
// 245.774 us; speedup vs baseline: 1.2776x; 1.2776x over previous
//
#include <hip/hip_runtime.h>
#include <math.h>

#define NPTS    131072
#define FEAT    64
#define KCLUS   2048
#define CHUNKC  256      // clusters staged per LDS chunk (== blockDim)
#define NCHUNK  (KCLUS / CHUNKC)   // 8
#define PPW     32       // points per wave (2 MFMA row-tiles)
#define WPB     4        // waves per 256-thread block (wave = 64 on CDNA!)
#define PPB     (PPW * WPB)   // 128 points per block
#define CANDC   10       // per-lane register candidate slots

typedef __attribute__((ext_vector_type(8))) short frag_ab;   // 8 bf16
typedef __attribute__((ext_vector_type(4))) float frag_cd;   // 4 fp32 acc

// fp32 -> bf16 RNE
__device__ __forceinline__ short f2bf(float f) {
    unsigned u = __float_as_uint(f);
    u += 0x7FFFu + ((u >> 16) & 1u);
    return (short)(u >> 16);
}

// Exact fp32 distance term (cn - 2 x.c): IDENTICAL single-chain FMA order to
// rounds 1-3/7/9/10 (matches numpy argmin on this data, absmax 0 x7).
__device__ __forceinline__ float exact_dist(const float* __restrict__ x,
                                            const float* __restrict__ c,
                                            float cnv, int p, int kk) {
    const float4* xr4 = (const float4*)&x[(size_t)p * FEAT];
    const float4* cr4 = (const float4*)&c[(size_t)kk * FEAT];
    float s = 0.f;
#pragma unroll
    for (int j = 0; j < 16; ++j) {
        float4 a4 = xr4[j], b4 = cr4[j];
        s = fmaf(a4.x, b4.x, s); s = fmaf(a4.y, b4.y, s);
        s = fmaf(a4.z, b4.z, s); s = fmaf(a4.w, b4.w, s);
    }
    return fmaf(-2.f, s, cnv);
}

// ---------------------------------------------------------------------------
// cprep: exact fp32 cnorm, cbs_t = bf16(-2c) part-major [part=f/8][k][8]
// (proven conflict-free + correct B layout), cmax = max||c||.
// ---------------------------------------------------------------------------
__global__ void cprep_kernel(const float* __restrict__ c, float* __restrict__ cnorm,
                             short* __restrict__ cbs_t, float* __restrict__ cmax) {
    int k = blockIdx.x * blockDim.x + threadIdx.x;
    if (k >= KCLUS) return;
    const float4* row = (const float4*)&c[k * FEAT];
    float s = 0.f;
#pragma unroll
    for (int j = 0; j < 16; ++j) {
        float4 v = row[j];
        s = fmaf(v.x, v.x, s); s = fmaf(v.y, v.y, s);
        s = fmaf(v.z, v.z, s); s = fmaf(v.w, v.w, s);
        short4 b;
        b.x = f2bf(-2.f * v.x); b.y = f2bf(-2.f * v.y);
        b.z = f2bf(-2.f * v.z); b.w = f2bf(-2.f * v.w);
        *(short4*)&cbs_t[((size_t)(j >> 1) * KCLUS + k) * 8 + (j & 1) * 4] = b;
    }
    cnorm[k] = s;
    atomicMax((int*)cmax, __float_as_int(sqrtf(s)));  // positive: int-max == float-max
}

// Prefetch one 256-cluster chunk into registers (8 x 16B global loads + norm).
__device__ __forceinline__ void load_chunk(const short* __restrict__ cbs_t,
                                           const float* __restrict__ cnorm,
                                           int k0, int tid,
                                           frag_ab pre[8], float* cnpre) {
#pragma unroll
    for (int p8 = 0; p8 < 8; ++p8)
        pre[p8] = *(const frag_ab*)&cbs_t[((size_t)p8 * KCLUS + k0 + tid) * 8];
    *cnpre = cnorm[k0 + tid];
}

// ---------------------------------------------------------------------------
// Assign: r9's kernel (172 us, absmax 0) with two proven splices: inline ||x||
// butterfly (r10-pass2-proven, kills xprep/xn) and a16 output write (kills
// decode). Everything else byte-identical to r9.
// ---------------------------------------------------------------------------
__global__ __launch_bounds__(256) void assign_kernel(
    const float* __restrict__ x, const float* __restrict__ c,
    const short* __restrict__ cbs_t, const float* __restrict__ cnorm,
    const float* __restrict__ cmaxp,
    float* __restrict__ out_assign, unsigned short* __restrict__ a16)
{
    __shared__ short csh[8 * CHUNKC * 8];   // 32 KB part-major staging
    __shared__ float cnsh[CHUNKC];          // 1 KB

    const int tid = threadIdx.x, wv = tid >> 6, lane = tid & 63;
    const int col = lane & 15, q = lane >> 4;
    const int pt0 = blockIdx.x * PPB + wv * PPW;

    // A-frags (proven layout) + inline row norms (r10-pass2-proven butterfly
    // over lane bits 16/32: lane's 16 feats of row rt*16+col -> full norm).
    frag_ab A[2][2];
    float nrm[2];
#pragma unroll
    for (int rt = 0; rt < 2; ++rt) {
        float ps = 0.f;
#pragma unroll
        for (int kh = 0; kh < 2; ++kh) {
            const float4* xp = (const float4*)&x[(size_t)(pt0 + rt * 16 + col) * FEAT + kh * 32 + q * 8];
            float4 v0 = xp[0], v1 = xp[1];
            frag_ab a;
            a[0] = f2bf(v0.x); a[1] = f2bf(v0.y); a[2] = f2bf(v0.z); a[3] = f2bf(v0.w);
            a[4] = f2bf(v1.x); a[5] = f2bf(v1.y); a[6] = f2bf(v1.z); a[7] = f2bf(v1.w);
            A[rt][kh] = a;
            ps = fmaf(v0.x, v0.x, ps); ps = fmaf(v0.y, v0.y, ps);
            ps = fmaf(v0.z, v0.z, ps); ps = fmaf(v0.w, v0.w, ps);
            ps = fmaf(v1.x, v1.x, ps); ps = fmaf(v1.y, v1.y, ps);
            ps = fmaf(v1.z, v1.z, ps); ps = fmaf(v1.w, v1.w, ps);
        }
        ps += __shfl_xor(ps, 16);
        ps += __shfl_xor(ps, 32);
        nrm[rt] = sqrtf(ps);
    }

    float m[2][4];
#pragma unroll
    for (int rt = 0; rt < 2; ++rt)
#pragma unroll
        for (int r = 0; r < 4; ++r) m[rt][r] = INFINITY;

    frag_ab pre[8];
    float   cnpre;

    // ------------------- PASS 1: approx min (registers only) --------------
    load_chunk(cbs_t, cnorm, 0, tid, pre, &cnpre);
    for (int c8 = 0; c8 < NCHUNK; ++c8) {
        __syncthreads();
#pragma unroll
        for (int p8 = 0; p8 < 8; ++p8)
            *(frag_ab*)&csh[(p8 * CHUNKC + tid) * 8] = pre[p8];
        cnsh[tid] = cnpre;
        __syncthreads();
        if (c8 < NCHUNK - 1)
            load_chunk(cbs_t, cnorm, (c8 + 1) * CHUNKC, tid, pre, &cnpre);  // overlaps compute

#pragma unroll 4
        for (int ct = 0; ct < CHUNKC / 16; ++ct) {
            const int lc = ct * 16 + col;
            frag_ab b0 = *(const frag_ab*)&csh[(q * CHUNKC + lc) * 8];
            frag_ab b1 = *(const frag_ab*)&csh[((4 + q) * CHUNKC + lc) * 8];
            const float cnv = cnsh[lc];
#pragma unroll
            for (int rt = 0; rt < 2; ++rt) {
                frag_cd acc = {cnv, cnv, cnv, cnv};
                acc = __builtin_amdgcn_mfma_f32_16x16x32_bf16(A[rt][0], b0, acc, 0, 0, 0);
                acc = __builtin_amdgcn_mfma_f32_16x16x32_bf16(A[rt][1], b1, acc, 0, 0, 0);
                m[rt][0] = fminf(m[rt][0], acc[0]);
                m[rt][1] = fminf(m[rt][1], acc[1]);
                m[rt][2] = fminf(m[rt][2], acc[2]);
                m[rt][3] = fminf(m[rt][3], acc[3]);
            }
        }
    }

    // Threshold: m~ + 0.034*||x||*cmax >= m~ + 2*eps_bf16 (proven margin).
    const float cmax = *cmaxp;
    float t[2][4];
#pragma unroll
    for (int rt = 0; rt < 2; ++rt)
#pragma unroll
        for (int r = 0; r < 4; ++r) {
            float mm = m[rt][r];
            mm = fminf(mm, __shfl_xor(mm, 1));
            mm = fminf(mm, __shfl_xor(mm, 2));
            mm = fminf(mm, __shfl_xor(mm, 4));
            mm = fminf(mm, __shfl_xor(mm, 8));
            float xnp = __shfl(nrm[rt], q * 4 + r);   // lane q*4+r holds that row's norm
            t[rt][r] = mm + 0.034f * xnp * cmax;
        }

    // ------------------- PASS 2: per-lane register capture -----------------
    unsigned codes[CANDC];
    int ccnt = 0;

    load_chunk(cbs_t, cnorm, 0, tid, pre, &cnpre);
    for (int c8 = 0; c8 < NCHUNK; ++c8) {
        __syncthreads();
#pragma unroll
        for (int p8 = 0; p8 < 8; ++p8)
            *(frag_ab*)&csh[(p8 * CHUNKC + tid) * 8] = pre[p8];
        cnsh[tid] = cnpre;
        __syncthreads();
        if (c8 < NCHUNK - 1)
            load_chunk(cbs_t, cnorm, (c8 + 1) * CHUNKC, tid, pre, &cnpre);

        const int k0 = c8 * CHUNKC;
#pragma unroll 2
        for (int ct = 0; ct < CHUNKC / 16; ++ct) {
            const int lc = ct * 16 + col;
            frag_ab b0 = *(const frag_ab*)&csh[(q * CHUNKC + lc) * 8];
            frag_ab b1 = *(const frag_ab*)&csh[((4 + q) * CHUNKC + lc) * 8];
            const float cnv = cnsh[lc];
            const int kk = k0 + lc;
#pragma unroll
            for (int rt = 0; rt < 2; ++rt) {
                frag_cd acc = {cnv, cnv, cnv, cnv};
                acc = __builtin_amdgcn_mfma_f32_16x16x32_bf16(A[rt][0], b0, acc, 0, 0, 0);
                acc = __builtin_amdgcn_mfma_f32_16x16x32_bf16(A[rt][1], b1, acc, 0, 0, 0);
#pragma unroll
                for (int r = 0; r < 4; ++r) {
                    if (acc[r] <= t[rt][r]) {   // rare
                        unsigned code = ((unsigned)(rt * 16 + q * 4 + r) << 11) | (unsigned)kk;
#pragma unroll
                        for (int s = 0; s < CANDC; ++s)   // register-file push
                            if (s == ccnt) codes[s] = code;
                        ccnt++;
                    }
                }
            }
        }
    }

    // ------------------- exact refine (per-lane, registers) ----------------
    const bool anyovf = __any(ccnt > CANDC);

    if (!anyovf) {
        float bestd[2][4];
        int   bestk[2][4];
#pragma unroll
        for (int rt = 0; rt < 2; ++rt)
#pragma unroll
            for (int r = 0; r < 4; ++r) { bestd[rt][r] = INFINITY; bestk[rt][r] = 0x7fffffff; }

        for (int i = 0; i < CANDC; ++i) {
            if (i < ccnt) {
                unsigned code = codes[i];
                int pl = (int)(code >> 11), kk = (int)(code & 2047u);
                float e = exact_dist(x, c, cnorm[kk], pt0 + pl, kk);
                int crt = pl >> 4, cr = pl & 3;
#pragma unroll
                for (int rt = 0; rt < 2; ++rt)
#pragma unroll
                    for (int r = 0; r < 4; ++r)
                        if (crt == rt && cr == r &&
                            (e < bestd[rt][r] || (e == bestd[rt][r] && kk < bestk[rt][r]))) {
                            bestd[rt][r] = e; bestk[rt][r] = kk;
                        }
            }
        }

        // Proven cross-lane (d,k) reduce + col==0 writes (float4 + ushort4).
#pragma unroll
        for (int rt = 0; rt < 2; ++rt) {
#pragma unroll
            for (int r = 0; r < 4; ++r) {
                float bd = bestd[rt][r]; int bk = bestk[rt][r];
#pragma unroll
                for (int mask = 1; mask <= 8; mask <<= 1) {
                    float od = __shfl_xor(bd, mask);
                    int   ok = __shfl_xor(bk, mask);
                    if (od < bd || (od == bd && ok < bk)) { bd = od; bk = ok; }
                }
                bestd[rt][r] = bd; bestk[rt][r] = bk;
            }
            if (col == 0) {
                float4 w = { (float)bestk[rt][0], (float)bestk[rt][1],
                             (float)bestk[rt][2], (float)bestk[rt][3] };
                *(float4*)&out_assign[pt0 + rt * 16 + q * 4] = w;
                ushort4 u = { (unsigned short)bestk[rt][0], (unsigned short)bestk[rt][1],
                              (unsigned short)bestk[rt][2], (unsigned short)bestk[rt][3] };
                *(ushort4*)&a16[pt0 + rt * 16 + q * 4] = u;
            }
        }
    } else {
        // Overflow (rare): whole-wave fully-exact argmin, no thresholds.
        for (int pp = 0; pp < PPW; ++pp) {
            const int p = pt0 + pp;
            float bd = INFINITY; int bk = 0x7fffffff;
            for (int kk = lane; kk < KCLUS; kk += 64) {
                float e = exact_dist(x, c, cnorm[kk], p, kk);
                if (e < bd || (e == bd && kk < bk)) { bd = e; bk = kk; }
            }
#pragma unroll
            for (int mask = 1; mask <= 32; mask <<= 1) {
                float od = __shfl_xor(bd, mask);
                int   ok = __shfl_xor(bk, mask);
                if (od < bd || (od == bd && ok < bk)) { bd = od; bk = ok; }
            }
            if (lane == 0) {
                out_assign[p] = (float)bk;
                a16[p] = (unsigned short)bk;
            }
        }
    }
}

// ---------------------------------------------------------------------------
// Scatter (r10-proven, verbatim): block (cg, slice) owns clusters [8cg,8cg+8)
// over point slice [slice*16384, +16384). Ballot-collect, per-wave LDS
// accumulate, 8 atomic rows per block.
// ---------------------------------------------------------------------------
__global__ void scatter_kernel(const float* __restrict__ x,
                               const unsigned short* __restrict__ a16,
                               float* __restrict__ sums, int* __restrict__ counts) {
    __shared__ float wsum[4][8][64];   // 8 KB, per-wave private
    __shared__ int   wcnt[4][8];

    const int tid = threadIdx.x, wv = tid >> 6, lane = tid & 63;
    const int c0 = blockIdx.x * 8;

    for (int idx = tid; idx < 4 * 8 * 64; idx += 256) ((float*)wsum)[idx] = 0.f;
    if (tid < 32) ((int*)wcnt)[tid] = 0;
    __syncthreads();

    const int base = blockIdx.y * 16384 + wv * 4096;
#pragma unroll 1
    for (int it = 0; it < 64; ++it) {
        const int pbase = base + it * 64;
        int a = (int)a16[pbase + lane];                    // coalesced 128B
        unsigned long long mask = __ballot(a >= c0 && a < c0 + 8);
        while (mask) {
            int j = __ffsll((long long)mask) - 1;
            mask &= mask - 1;
            int cl = __shfl(a, j) - c0;
            float xv = x[(size_t)(pbase + j) * FEAT + lane];  // coalesced 256B row
            wsum[wv][cl][lane] += xv;                         // own slice: no race
            if (lane == 0) wcnt[wv][cl] += 1;
        }
    }
    __syncthreads();

    for (int idx = tid; idx < 512; idx += 256) {
        int cl = idx >> 6, ln = idx & 63;
        float s = wsum[0][cl][ln] + wsum[1][cl][ln] + wsum[2][cl][ln] + wsum[3][cl][ln];
        atomicAdd(&sums[(size_t)(c0 + cl) * FEAT + ln], s);
    }
    if (tid < 8) {
        int cc = wcnt[0][tid] + wcnt[1][tid] + wcnt[2][tid] + wcnt[3][tid];
        if (cc) atomicAdd(&counts[c0 + tid], cc);
    }
}

__global__ void update_kernel(const float* __restrict__ c,
                              const float* __restrict__ sums,
                              const int* __restrict__ counts,
                              float* __restrict__ out_upd) {
    int i = blockIdx.x * blockDim.x + threadIdx.x;
    if (i < KCLUS * FEAT) {
        int   k   = i >> 6;
        float cv  = c[i];
        int   cnt = counts[k];
        float nc  = (cnt > 0) ? (sums[i] / (float)cnt) : cv;
        out_upd[i] = 0.99f * cv + 0.01f * nc;
    }
}

extern "C" void kernel_launch(void* const* d_in, const int* in_sizes, int n_in,
                              void* d_out, int out_size, void* d_ws, size_t ws_size,
                              hipStream_t stream) {
    const float* x = (const float*)d_in[0];
    const float* c = (const float*)d_in[1];

    float* out        = (float*)d_out;
    float* out_assign = out;          // [0, N): assignments as float
    float* out_upd    = out + NPTS;   // [N, N + K*FEAT)

    // Workspace ~1.06 MB.
    char* ws = (char*)d_ws;
    constexpr size_t O_CNORM = 0;                       // 8 KB
    constexpr size_t O_CBS   = 8192;                    // 256 KB
    constexpr size_t O_ZERO  = 8192 + 262144;           // 270336
    constexpr size_t O_CMAX  = O_ZERO;                  // 64 B
    constexpr size_t O_SUMS  = O_ZERO + 64;             // 512 KB
    constexpr size_t O_CNTS  = O_SUMS + 524288;         // 8 KB
    constexpr size_t ZERO_LEN = 64 + 524288 + 8192;     // 532544
    constexpr size_t O_A16   = O_ZERO + ZERO_LEN;       // 802880, 256 KB

    float*    cnorm  = (float*)(ws + O_CNORM);
    short*    cbs_t  = (short*)(ws + O_CBS);
    float*    cmax   = (float*)(ws + O_CMAX);
    float*    sums   = (float*)(ws + O_SUMS);
    int*      counts = (int*)(ws + O_CNTS);
    unsigned short* a16 = (unsigned short*)(ws + O_A16);

    hipMemsetAsync(ws + O_ZERO, 0, ZERO_LEN, stream);

    cprep_kernel<<<KCLUS / 256, 256, 0, stream>>>(c, cnorm, cbs_t, cmax);
    // 4 waves/block x 32 pts/wave = 128 pts/block -> grid NPTS/128 (wave=64!)
    assign_kernel<<<NPTS / PPB, 256, 0, stream>>>(x, c, cbs_t, cnorm, cmax,
                                                  out_assign, a16);
    scatter_kernel<<<dim3(KCLUS / 8, 8), 256, 0, stream>>>(x, a16, sums, counts);
    update_kernel<<<(KCLUS * FEAT) / 256, 256, 0, stream>>>(c, sums, counts, out_upd);
}